// Round 2
// baseline (390.799 us; speedup 1.0000x reference)
//
#include <hip/hip_runtime.h>

#define NN   8192
#define DIN  512
#define H1   32
#define H2   16
#define NE   262144
#define EPSV 1e-32f

// ---------------- k1: XW0 = X @ W0   [NN x H1] ----------------
__global__ __launch_bounds__(256) void k_xw0(const float* __restrict__ X,
                                             const float* __restrict__ W0,
                                             float* __restrict__ XW0) {
    int t = blockIdx.x * 256 + threadIdx.x;
    int r = t >> 5, c = t & 31;
    const float4* Xr = reinterpret_cast<const float4*>(X + (size_t)r * DIN);
    float acc = 0.f;
#pragma unroll 8
    for (int k4 = 0; k4 < DIN / 4; ++k4) {
        float4 x = Xr[k4];
        int k = k4 * 4;
        acc = fmaf(x.x, W0[(k + 0) * H1 + c], acc);
        acc = fmaf(x.y, W0[(k + 1) * H1 + c], acc);
        acc = fmaf(x.z, W0[(k + 2) * H1 + c], acc);
        acc = fmaf(x.w, W0[(k + 3) * H1 + c], acc);
    }
    XW0[t] = acc;
}

// ---------------- CSR build: histogram -> scan -> scatter ----------------
__global__ __launch_bounds__(256) void k_hist(const int* __restrict__ er,
                                              int* __restrict__ cnt) {
    int e = blockIdx.x * 256 + threadIdx.x;
    atomicAdd(&cnt[er[e]], 1);
}

// single block, 1024 threads, 8 bins each: exclusive scan over 8192 counts
__global__ __launch_bounds__(1024) void k_scan(const int* __restrict__ cnt,
                                               int* __restrict__ rptr,
                                               int* __restrict__ rfill) {
    __shared__ int part[1024];
    int tid = threadIdx.x;
    int local[8];
    int s = 0;
#pragma unroll
    for (int i = 0; i < 8; ++i) { local[i] = s; s += cnt[tid * 8 + i]; }
    part[tid] = s;
    __syncthreads();
    for (int off = 1; off < 1024; off <<= 1) {
        int v = (tid >= off) ? part[tid - off] : 0;
        __syncthreads();
        part[tid] += v;
        __syncthreads();
    }
    int base = (tid == 0) ? 0 : part[tid - 1];
#pragma unroll
    for (int i = 0; i < 8; ++i) {
        rptr[tid * 8 + i]  = base + local[i];
        rfill[tid * 8 + i] = base + local[i];
    }
    if (tid == 1023) rptr[8192] = part[1023];
}

__global__ __launch_bounds__(256) void k_scatter(const int* __restrict__ er,
                                                 const int* __restrict__ ec,
                                                 const float* __restrict__ ev,
                                                 int* __restrict__ rfill,
                                                 int* __restrict__ ccol,
                                                 float* __restrict__ cval) {
    int e = blockIdx.x * 256 + threadIdx.x;
    int p = atomicAdd(&rfill[er[e]], 1);
    ccol[p] = ec[e];
    cval[p] = ev[e];
}

// ---------------- k2: hacc[r,c] = sum_p cval[p] * XW0[ccol[p], c]  (pull) ----------------
// 32 lanes per row (feature c). Edge meta broadcasts within the half-wave;
// XW0 row read is 128B contiguous, L2-resident (1 MB). Zero atomics.
__global__ __launch_bounds__(256) void k_spmm1(const int* __restrict__ rptr,
                                               const int* __restrict__ ccol,
                                               const float* __restrict__ cval,
                                               const float* __restrict__ XW0,
                                               float* __restrict__ hacc) {
    int t = blockIdx.x * 256 + threadIdx.x;
    int r = t >> 5, c = t & 31;
    int p = rptr[r], end = rptr[r + 1];
    float a0 = 0.f, a1 = 0.f;
    for (; p + 2 <= end; p += 2) {
        a0 = fmaf(cval[p],     XW0[ccol[p]     * H1 + c], a0);
        a1 = fmaf(cval[p + 1], XW0[ccol[p + 1] * H1 + c], a1);
    }
    if (p < end) a0 = fmaf(cval[p], XW0[ccol[p] * H1 + c], a0);
    hacc[t] = a0 + a1;
}

// ---------------- k3: HW1 = relu(hacc) @ W1   [NN x H2] ----------------
__global__ __launch_bounds__(256) void k_hw1(const float* __restrict__ hacc,
                                             const float* __restrict__ W1,
                                             float* __restrict__ HW1) {
    int t = blockIdx.x * 256 + threadIdx.x;
    int r = t >> 4, c = t & 15;
    const float* hr = hacc + r * H1;
    float acc = 0.f;
#pragma unroll
    for (int k = 0; k < H1; ++k)
        acc = fmaf(fmaxf(hr[k], 0.f), W1[k * H2 + c], acc);
    HW1[t] = acc;
}

// ---------------- k4: mean[r,c] = sum_p cval[p] * HW1[ccol[p], c]  (pull) ----------------
__global__ __launch_bounds__(256) void k_spmm2(const int* __restrict__ rptr,
                                               const int* __restrict__ ccol,
                                               const float* __restrict__ cval,
                                               const float* __restrict__ HW1,
                                               float* __restrict__ mean) {
    int t = blockIdx.x * 256 + threadIdx.x;
    int r = t >> 4, c = t & 15;
    int p = rptr[r], end = rptr[r + 1];
    float a0 = 0.f, a1 = 0.f;
    for (; p + 2 <= end; p += 2) {
        a0 = fmaf(cval[p],     HW1[ccol[p]     * H2 + c], a0);
        a1 = fmaf(cval[p + 1], HW1[ccol[p + 1] * H2 + c], a1);
    }
    if (p < end) a0 = fmaf(cval[p], HW1[ccol[p] * H2 + c], a0);
    mean[t] = a0 + a1;
}

// ---------------- k5: out = sigmoid(Z @ Z^T), Z = max(mean, EPS) ----------------
#define TI  128
#define PAD 20

__device__ __forceinline__ float sigm(float x) {
    return __fdividef(1.0f, 1.0f + __expf(-x));
}

__global__ __launch_bounds__(256) void k_decode(const float* __restrict__ Zm,
                                                float* __restrict__ out) {
    __shared__ float zi[TI * PAD];
    __shared__ float zj[TI * PAD];
    const int i0 = blockIdx.y * TI, j0 = blockIdx.x * TI;
    const int tid = threadIdx.x;

#pragma unroll
    for (int l = 0; l < 2; ++l) {
        int t = tid + l * 256;
        int r = t >> 2, c4 = (t & 3) * 4;
        float4 a = *reinterpret_cast<const float4*>(Zm + (size_t)(i0 + r) * H2 + c4);
        float4 b = *reinterpret_cast<const float4*>(Zm + (size_t)(j0 + r) * H2 + c4);
        a.x = fmaxf(a.x, EPSV); a.y = fmaxf(a.y, EPSV);
        a.z = fmaxf(a.z, EPSV); a.w = fmaxf(a.w, EPSV);
        b.x = fmaxf(b.x, EPSV); b.y = fmaxf(b.y, EPSV);
        b.z = fmaxf(b.z, EPSV); b.w = fmaxf(b.w, EPSV);
        *reinterpret_cast<float4*>(&zi[r * PAD + c4]) = a;
        *reinterpret_cast<float4*>(&zj[r * PAD + c4]) = b;
    }
    __syncthreads();

    const int tx = tid & 15, ty = tid >> 4;
    float acc[8][8] = {};
#pragma unroll
    for (int k4 = 0; k4 < 4; ++k4) {
        float4 ra[8], rb[8];
#pragma unroll
        for (int a = 0; a < 8; ++a)
            ra[a] = *reinterpret_cast<const float4*>(&zi[(ty * 8 + a) * PAD + k4 * 4]);
#pragma unroll
        for (int b = 0; b < 8; ++b)
            rb[b] = *reinterpret_cast<const float4*>(&zj[(tx * 8 + b) * PAD + k4 * 4]);
#pragma unroll
        for (int a = 0; a < 8; ++a)
#pragma unroll
            for (int b = 0; b < 8; ++b) {
                acc[a][b] = fmaf(ra[a].x, rb[b].x, acc[a][b]);
                acc[a][b] = fmaf(ra[a].y, rb[b].y, acc[a][b]);
                acc[a][b] = fmaf(ra[a].z, rb[b].z, acc[a][b]);
                acc[a][b] = fmaf(ra[a].w, rb[b].w, acc[a][b]);
            }
    }

#pragma unroll
    for (int a = 0; a < 8; ++a) {
        size_t rowbase = (size_t)(i0 + ty * 8 + a) * NN + j0 + tx * 8;
#pragma unroll
        for (int b4 = 0; b4 < 8; b4 += 4) {
            float4 o;
            o.x = sigm(acc[a][b4 + 0]);
            o.y = sigm(acc[a][b4 + 1]);
            o.z = sigm(acc[a][b4 + 2]);
            o.w = sigm(acc[a][b4 + 3]);
            *reinterpret_cast<float4*>(out + rowbase + b4) = o;
        }
    }
}

extern "C" void kernel_launch(void* const* d_in, const int* in_sizes, int n_in,
                              void* d_out, int out_size, void* d_ws, size_t ws_size,
                              hipStream_t stream) {
    const float* X  = (const float*)d_in[0];
    const int*   er = (const int*)d_in[1];
    const int*   ec = (const int*)d_in[2];
    const float* ev = (const float*)d_in[3];
    const float* W0 = (const float*)d_in[4];
    const float* W1 = (const float*)d_in[5];
    // d_in[6] = W2: dead in eval path.
    float* out = (float*)d_out;

    char* ws = (char*)d_ws;
    float* XW0  = (float*)(ws);                          // 1 MB
    float* hacc = (float*)(ws + (1 << 20));              // 1 MB
    float* mean = (float*)(ws + (2 << 20));              // 512 KB
    float* HW1  = (float*)(ws + (2 << 20) + (512 << 10));// 512 KB
    int*   cnt  = (int*)  (ws + (3 << 20));              // 32 KB
    int*   rptr = (int*)  (ws + (3 << 20) + (64 << 10)); // 8193 ints
    int*   rfill= (int*)  (ws + (3 << 20) + (128 << 10));// 32 KB
    int*   ccol = (int*)  (ws + (3 << 20) + (192 << 10));// 1 MB
    float* cval = (float*)(ws + (4 << 20) + (192 << 10));// 1 MB

    hipMemsetAsync(cnt, 0, 32 << 10, stream);            // histogram zero-init

    k_xw0    <<<NN * H1 / 256, 256, 0, stream>>>(X, W0, XW0);
    k_hist   <<<NE / 256, 256, 0, stream>>>(er, cnt);
    k_scan   <<<1, 1024, 0, stream>>>(cnt, rptr, rfill);
    k_scatter<<<NE / 256, 256, 0, stream>>>(er, ec, ev, rfill, ccol, cval);
    k_spmm1  <<<NN * H1 / 256, 256, 0, stream>>>(rptr, ccol, cval, XW0, hacc);
    k_hw1    <<<NN * H2 / 256, 256, 0, stream>>>(hacc, W1, HW1);
    k_spmm2  <<<NN * H2 / 256, 256, 0, stream>>>(rptr, ccol, cval, HW1, mean);
    k_decode <<<dim3(NN / TI, NN / TI), 256, 0, stream>>>(mean, out);
}